// Round 12
// baseline (551.947 us; speedup 1.0000x reference)
//
#include <hip/hip_runtime.h>
#include <stdint.h>

#define ALPHA 0.3f
#define CLAMPV 0.3f
#define BDIM 4096
#define NDIM 1024

typedef float f32x4 __attribute__((ext_vector_type(4)));
typedef __bf16 bf16x8 __attribute__((ext_vector_type(8)));

union U16x8 { uint4 v; unsigned short u[8]; };
union U16x4 { uint2 v; unsigned short u[4]; };

__device__ __forceinline__ float bf2f(unsigned short u) {
  union { unsigned int i; float f; } c; c.i = ((unsigned int)u) << 16; return c.f;
}
__device__ __forceinline__ unsigned short f2bf(float f) {
  union { float f; unsigned int i; } c; c.f = f;
  unsigned int u = c.i;
  unsigned int r = u + 0x7FFFu + ((u >> 16) & 1u);
  return (unsigned short)(r >> 16);
}

// ---------------------------------------------------------------------------
__global__ __launch_bounds__(256) void fill_k(float* __restrict__ out, int n) {
  int i = blockIdx.x * 256 + threadIdx.x;
  if (i < n) out[i] = 12345.0f;
}

// ---------------------------------------------------------------------------
__global__ __launch_bounds__(256) void split_x_k(const float* __restrict__ x,
                                                 unsigned short* __restrict__ hi,
                                                 unsigned short* __restrict__ lo) {
  const size_t i0 = ((size_t)blockIdx.x * 256 + threadIdx.x) * 8;
  f32x4 a = *(const f32x4*)(x + i0);
  f32x4 b = *(const f32x4*)(x + i0 + 4);
  U16x8 h8, l8;
#pragma unroll
  for (int i = 0; i < 4; ++i) {
    unsigned short h = f2bf(a[i]); h8.u[i] = h; l8.u[i] = f2bf(a[i] - bf2f(h));
    unsigned short h2 = f2bf(b[i]); h8.u[4+i] = h2; l8.u[4+i] = f2bf(b[i] - bf2f(h2));
  }
  *(uint4*)(hi + i0) = h8.v;
  *(uint4*)(lo + i0) = l8.v;
}

// ---------------------------------------------------------------------------
// batched tiled transpose (s2: Weff^T + x^T; s8': h1 -> h1T mode 0)
// ---------------------------------------------------------------------------
struct TDesc {
  const void* in1; const void* in2; const float* Wp;
  unsigned short* out_hi; unsigned short* out_lo;
  int R, C, tilesC, mode;
};
struct TBatch { TDesc d[8]; int start[9]; int n; };

__global__ __launch_bounds__(256) void transpose_k(TBatch batch) {
  const int bid = blockIdx.x;
  int g = 0;
#pragma unroll
  for (int i = 1; i < 8; ++i)
    if (i < batch.n && bid >= batch.start[i]) g = i;
  TDesc D = batch.d[g];
  const int lt = bid - batch.start[g];
  const int trow = lt / D.tilesC;
  const int tcol = lt - trow * D.tilesC;
  const int r0 = trow * 64, c0 = tcol * 64;

  __shared__ float tile[64][65];
  const int t = threadIdx.x;
  const int sub = t >> 3, oct = t & 7;
  const float Wv = (D.mode == 2) ? *D.Wp : 0.f;

#pragma unroll
  for (int p = 0; p < 2; ++p) {
    const int rl = p * 32 + sub;
    const int cl0 = oct * 8;
    float vv[8];
    if (D.mode == 0) {
      const unsigned short* ip = (const unsigned short*)D.in1 + (size_t)(r0 + rl) * D.C + c0 + cl0;
      U16x8 tmp; tmp.v = *(const uint4*)ip;
#pragma unroll
      for (int i = 0; i < 8; ++i) vv[i] = bf2f(tmp.u[i]);
    } else {
      const float* ip = (const float*)D.in1 + (size_t)(r0 + rl) * D.C + c0 + cl0;
      f32x4 a = *(const f32x4*)ip, b = *(const f32x4*)(ip + 4);
#pragma unroll
      for (int i = 0; i < 4; ++i) { vv[i] = a[i]; vv[4+i] = b[i]; }
      if (D.mode == 2) {
        const float* ip2 = (const float*)D.in2 + (size_t)(r0 + rl) * D.C + c0 + cl0;
        f32x4 c = *(const f32x4*)ip2, d2 = *(const f32x4*)(ip2 + 4);
#pragma unroll
        for (int i = 0; i < 4; ++i) { vv[i] += Wv * c[i]; vv[4+i] += Wv * d2[i]; }
      }
    }
#pragma unroll
    for (int i = 0; i < 8; ++i) tile[cl0 + i][rl] = vv[i];
  }
  __syncthreads();
#pragma unroll
  for (int p = 0; p < 2; ++p) {
    const int cl = p * 32 + sub;
    const int rl0 = oct * 8;
    U16x8 h8, l8;
#pragma unroll
    for (int i = 0; i < 8; ++i) {
      float v = tile[cl][rl0 + i];
      unsigned short h = f2bf(v);
      h8.u[i] = h;
      l8.u[i] = f2bf(v - bf2f(h));
    }
    const size_t o = (size_t)(c0 + cl) * D.R + r0 + rl0;
    *(uint4*)(D.out_hi + o) = h8.v;
    if (D.mode != 0) *(uint4*)(D.out_lo + o) = l8.v;
  }
}

// ---------------------------------------------------------------------------
// batched MFMA GEMM v9: K-loop identical to v8 (verified: vmcnt 8/6/0, no
// T1/T5). NEW: fused-transpose epilogue — a thread's acc quad (4 consecutive
// rows, fixed col) is 8B-contiguous in the TRANSPOSED matrix; fg-adjacent
// lanes extend to 32B and L2 merges lines across the i-loop. Emits:
//   out32a/out32b (f32 row-major), sp (row-major split of rv=relu(v+addin)),
//   tr (transposed split of v), spT (transposed split of rv).
// This replaces the standalone f32->split transpose kernels (s4/s6/s8) and
// kills the F0/F2 f32 intermediates. Values bit-identical (same f32 -> f2bf).
// ---------------------------------------------------------------------------
struct GemmDesc {
  const unsigned short *Ahi, *Alo, *Bhi, *Blo;
  int lda, ldb, nk, accadd;     // nk = K/32 steps per phase
  float* out32a;
  float* out32b;
  const float* addin;
  unsigned short* sp_hi;        // row-major split of rv
  unsigned short* sp_lo;
  unsigned short* tr_hi;        // [NDIM][BDIM] transposed split of v
  unsigned short* tr_lo;
  unsigned short* spT_hi;       // [NDIM][BDIM] transposed split of rv
  unsigned short* spT_lo;
};
struct GemmBatch { GemmDesc d[16]; int start[17]; int n; };

#define AS1 __attribute__((address_space(1)))
#define AS3 __attribute__((address_space(3)))

__global__ __launch_bounds__(256, 2) void gemm_k(GemmBatch batch) {
  const int bid = blockIdx.x;
  int g = 0;
#pragma unroll
  for (int i = 1; i < 16; ++i)
    if (i < batch.n && bid >= batch.start[i]) g = i;
  GemmDesc D = batch.d[g];
  const int local = bid - batch.start[g];
  const int tm = local >> 3;        // tilesN fixed at 8 (N=1024)
  const int tn = local & 7;

  // 2 buffers x (A 16KB | Bhi 8KB | Blo 8KB) = 64 KB
  __shared__ __align__(16) unsigned short LDS[32768];

  const int t = threadIdx.x;
  const int lane = t & 63;
  const int wave = t >> 6;
  const int wr = wave >> 1, wc = wave & 1;
  const int fr = lane & 15, fg = lane >> 4;

  f32x4 acc[8][4];
#pragma unroll
  for (int i = 0; i < 8; ++i)
#pragma unroll
    for (int j = 0; j < 4; ++j)
#pragma unroll
      for (int rr = 0; rr < 4; ++rr) acc[i][j][rr] = 0.f;

  // ---- staging geometry (linear LDS dest, pre-swizzled global source) ----
  const int r0 = t >> 2;                                    // 0..63
  const int colSwE = (((t & 3) ^ ((t >> 3) & 3)) << 3);     // element offset

  size_t aRow[4], bRow[2];
#pragma unroll
  for (int qq = 0; qq < 4; ++qq)
    aRow[qq] = (size_t)(tm * 256 + qq * 64 + r0) * D.lda + colSwE;
#pragma unroll
  for (int qq = 0; qq < 2; ++qq)
    bRow[qq] = (size_t)(tn * 128 + qq * 64 + r0) * D.ldb + colSwE;

  const int ldsW = wave * 512;    // wave-uniform elem offset within region

  auto stageA = [&](const unsigned short* P, int kb, int b) {
    unsigned short* base = LDS + b * 16384 + ldsW;
#pragma unroll
    for (int qq = 0; qq < 4; ++qq)
      __builtin_amdgcn_global_load_lds(
          (const AS1 void*)(P + aRow[qq] + kb),
          (AS3 void*)(base + qq * 2048), 16, 0, 0);
  };
  auto stageB = [&](const unsigned short* P, int region, int kb, int b) {
    unsigned short* base = LDS + b * 16384 + region + ldsW;
#pragma unroll
    for (int qq = 0; qq < 2; ++qq)
      __builtin_amdgcn_global_load_lds(
          (const AS1 void*)(P + bRow[qq] + kb),
          (AS3 void*)(base + qq * 2048), 16, 0, 0);
  };

  // ---- fragment ds_read byte offsets (swizzled) ----
  const int swz = ((fg ^ ((fr >> 1) & 3)) << 4);
  int aoff[8], boff[4];
#pragma unroll
  for (int i = 0; i < 8; ++i)
    aoff[i] = (wr * 128 + i * 16 + fr) * 64 + swz;
#pragma unroll
  for (int j = 0; j < 4; ++j)
    boff[j] = 16384 + (wc * 64 + j * 16 + fr) * 64 + swz;
  const char* ldsc = (const char*)LDS;

  auto computePh0 = [&](int b) {
    const char* bb = ldsc + b * 32768;
    bf16x8 af[8];
#pragma unroll
    for (int i = 0; i < 8; ++i) af[i] = *(const bf16x8*)(bb + aoff[i]);
#pragma unroll
    for (int j = 0; j < 4; ++j) {
      const bf16x8 bh = *(const bf16x8*)(bb + boff[j]);
#pragma unroll
      for (int i = 0; i < 8; ++i)
        acc[i][j] = __builtin_amdgcn_mfma_f32_16x16x32_bf16(af[i], bh, acc[i][j], 0, 0, 0);
      const bf16x8 bl = *(const bf16x8*)(bb + boff[j] + 8192);
#pragma unroll
      for (int i = 0; i < 8; ++i)
        acc[i][j] = __builtin_amdgcn_mfma_f32_16x16x32_bf16(af[i], bl, acc[i][j], 0, 0, 0);
    }
  };
  auto computePh1 = [&](int b) {
    const char* bb = ldsc + b * 32768;
    bf16x8 af[8];
#pragma unroll
    for (int i = 0; i < 8; ++i) af[i] = *(const bf16x8*)(bb + aoff[i]);
#pragma unroll
    for (int j = 0; j < 4; ++j) {
      const bf16x8 bh = *(const bf16x8*)(bb + boff[j]);
#pragma unroll
      for (int i = 0; i < 8; ++i)
        acc[i][j] = __builtin_amdgcn_mfma_f32_16x16x32_bf16(af[i], bh, acc[i][j], 0, 0, 0);
    }
  };

  const int n = D.nk;

  // ---- prologue: stage step 0 of phase 0 into buffer 0 (8 loads/wave) ----
  stageA(D.Ahi, 0, 0);
  stageB(D.Bhi, 8192, 0, 0);
  stageB(D.Blo, 12288, 0, 0);
  int buf = 0;

  // ---- phase 0 ----
#pragma unroll 1
  for (int kt = 0; kt < n; ++kt) {
    if (kt + 1 < n) {
      const int kb = (kt + 1) << 5;
      stageA(D.Ahi, kb, buf ^ 1);
      stageB(D.Bhi, 8192, kb, buf ^ 1);
      stageB(D.Blo, 12288, kb, buf ^ 1);
      asm volatile("s_waitcnt vmcnt(8)" ::: "memory");  // drain cur tile, keep 8 prefetch
    } else {
      stageA(D.Alo, 0, buf ^ 1);        // first step of phase 1 (6 loads/wave)
      stageB(D.Bhi, 8192, 0, buf ^ 1);
      asm volatile("s_waitcnt vmcnt(6)" ::: "memory");  // drain cur tile, keep 6 prefetch
    }
    __builtin_amdgcn_s_barrier();
    __builtin_amdgcn_sched_barrier(0);
    computePh0(buf);
    __builtin_amdgcn_sched_barrier(0);
    __builtin_amdgcn_s_barrier();
    buf ^= 1;
  }

  // ---- phase 1 ----
#pragma unroll 1
  for (int kt = 0; kt < n; ++kt) {
    if (kt + 1 < n) {
      const int kb = (kt + 1) << 5;
      stageA(D.Alo, kb, buf ^ 1);
      stageB(D.Bhi, 8192, kb, buf ^ 1);
      asm volatile("s_waitcnt vmcnt(6)" ::: "memory");  // drain cur tile, keep 6 prefetch
    } else {
      asm volatile("s_waitcnt vmcnt(0)" ::: "memory");
    }
    __builtin_amdgcn_s_barrier();
    __builtin_amdgcn_sched_barrier(0);
    computePh1(buf);
    __builtin_amdgcn_sched_barrier(0);
    __builtin_amdgcn_s_barrier();
    buf ^= 1;
  }

  // ---- fused epilogue ----
  const int grb = tm * 256 + wr * 128 + fg * 4;
  const int gcb = tn * 128 + wc * 64 + fr;
#pragma unroll
  for (int i = 0; i < 8; ++i) {
    const int gr0 = grb + i * 16;
#pragma unroll
    for (int j = 0; j < 4; ++j) {
      const int gc = gcb + j * 16;
      const f32x4 v = acc[i][j];
      f32x4 rv;
#pragma unroll
      for (int rr = 0; rr < 4; ++rr) {
        const size_t idx = (size_t)(gr0 + rr) * NDIM + gc;
        if (D.out32a) D.out32a[idx] = v[rr];
        if (D.out32b) D.out32b[idx] = D.accadd ? (D.out32b[idx] + v[rr]) : v[rr];
        const float tsum = v[rr] + (D.addin ? D.addin[idx] : 0.f);
        rv[rr] = fmaxf(tsum, 0.f);
        if (D.sp_hi) {
          const unsigned short h = f2bf(rv[rr]);
          D.sp_hi[idx] = h;
          D.sp_lo[idx] = f2bf(rv[rr] - bf2f(h));
        }
      }
      const size_t tb = (size_t)gc * BDIM + gr0;
      if (D.tr_hi) {
        U16x4 h2, l2;
#pragma unroll
        for (int rr = 0; rr < 4; ++rr) {
          const unsigned short h = f2bf(v[rr]);
          h2.u[rr] = h; l2.u[rr] = f2bf(v[rr] - bf2f(h));
        }
        *(uint2*)(D.tr_hi + tb) = h2.v;
        *(uint2*)(D.tr_lo + tb) = l2.v;
      }
      if (D.spT_hi) {
        U16x4 h2, l2;
#pragma unroll
        for (int rr = 0; rr < 4; ++rr) {
          const unsigned short h = f2bf(rv[rr]);
          h2.u[rr] = h; l2.u[rr] = f2bf(rv[rr] - bf2f(h));
        }
        *(uint2*)(D.spT_hi + tb) = h2.v;
        *(uint2*)(D.spT_lo + tb) = l2.v;
      }
    }
  }
}

// ---------------------------------------------------------------------------
// batched heb reduction: out = clamp(heb_in + ALPHA * sum(parts)), 1024
// blocks per desc.
// ---------------------------------------------------------------------------
struct HebRedB {
  const float* heb_in[3]; float* outp[3];
  const float* p[3][16]; int np[3]; int n;
};

__global__ __launch_bounds__(256) void hebred_k(HebRedB B) {
  const int g = blockIdx.x >> 10;
  const int local = blockIdx.x & 1023;
  const size_t i0 = ((size_t)local * 256 + threadIdx.x) * 4;
  f32x4 s = *(const f32x4*)(B.p[g][0] + i0);
#pragma unroll
  for (int k = 1; k < 16; ++k)
    if (k < B.np[g]) s += *(const f32x4*)(B.p[g][k] + i0);
  f32x4 h = *(const f32x4*)(B.heb_in[g] + i0);
  f32x4 o;
#pragma unroll
  for (int i = 0; i < 4; ++i) o[i] = fminf(fmaxf(h[i] + ALPHA * s[i], -CLAMPV), CLAMPV);
  *(f32x4*)(B.outp[g] + i0) = o;
}

// ---------------------------------------------------------------------------
__global__ __launch_bounds__(256) void yassm_k(const float* __restrict__ ysum,
                                               float* __restrict__ yout) {
  const int stride = gridDim.x * 256;
  for (int idx = blockIdx.x * 256 + threadIdx.x; idx < BDIM * 1022; idx += stride) {
    const int row = idx / 1022;
    const int col = idx - row * 1022;
    yout[idx] = ysum[(size_t)row * NDIM + col];
  }
}

__global__ __launch_bounds__(256) void tanhcol_k(const float* __restrict__ ysum,
                                                 float* __restrict__ wpart,
                                                 float* __restrict__ dpart) {
  const int r = blockIdx.x * 256 + threadIdx.x;
  const size_t b = (size_t)r * NDIM;
  float tw = tanhf(ysum[b + 1022]);
  float td = tanhf(ysum[b + 1021]);
#pragma unroll
  for (int o = 32; o > 0; o >>= 1) { tw += __shfl_down(tw, o); td += __shfl_down(td, o); }
  __shared__ float s1[4], s2[4];
  const int lane = threadIdx.x & 63, wv = threadIdx.x >> 6;
  if (lane == 0) { s1[wv] = tw; s2[wv] = td; }
  __syncthreads();
  if (threadIdx.x == 0) {
    wpart[blockIdx.x] = s1[0] + s1[1] + s1[2] + s1[3];
    dpart[blockIdx.x] = s2[0] + s2[1] + s2[2] + s2[3];
  }
}

__global__ void finalize_k(const float* __restrict__ wpart, const float* __restrict__ dpart,
                           float* __restrict__ out, int nout) {
  if (threadIdx.x == 0 && blockIdx.x == 0) {
    float s = 0.f, d = 0.f;
    for (int i = 0; i < 16; ++i) { s += wpart[i]; d += dpart[i]; }
    out[nout - 2] = s * (1.f / BDIM);
    out[nout - 1] = d * (1.f / BDIM);
  }
}

// ---------------------------------------------------------------------------
extern "C" void kernel_launch(void* const* d_in, const int* in_sizes, int n_in,
                              void* d_out, int out_size, void* d_ws, size_t ws_size,
                              hipStream_t stream) {
  const float* x = (const float*)d_in[0];
  const float* wbase[6]; const float* hebin[6];
  for (int i = 0; i < 6; ++i) { wbase[i] = (const float*)d_in[1 + i]; hebin[i] = (const float*)d_in[7 + i]; }
  const float* Wp = (const float*)d_in[13];
  float* out = (float*)d_out;
  const size_t YOUT = (size_t)BDIM * 1022;
  float* hebout[6];
  for (int i = 0; i < 6; ++i) hebout[i] = out + YOUT + (size_t)i * 1048576;

  // ---- workspace: 9 PAIR regions + 6 weight pairs + 2 f32 = 200 MiB ----
  const size_t E = (size_t)BDIM * NDIM;
  const size_t PAIRB = E * 4;                    // hi+lo bf16 pair (16 MiB)
  const size_t WPAIRB = (size_t)NDIM * NDIM * 4; // weight hi+lo pair (4 MiB)
  const size_t FB = E * 4;                       // f32 buffer (16 MiB)
  const size_t REQUIRED = 9 * PAIRB + 6 * WPAIRB + 2 * FB;   // 200 MiB

  if (ws_size < REQUIRED) {
    fill_k<<<(out_size + 255) / 256, 256, 0, stream>>>(out, out_size);
    return;
  }

  char* p = (char*)d_ws;
  auto takeB = [&](size_t n) -> char* { char* q = p; p += n; return q; };

  // lifetime-aliased regions (all transitions audited per dispatch):
  unsigned short* P0 = (unsigned short*)takeB(PAIRB);  // x pair -> h1 pair (s5)
  unsigned short* P1 = (unsigned short*)takeB(PAIRB);  // xT pair (dead after s5)
  unsigned short* P2 = (unsigned short*)takeB(PAIRB);  // h0 pair -> s7 part slot -> s9 parts 0-3
  unsigned short* P3 = (unsigned short*)takeB(PAIRB);  // h0T pair -> s9 parts 4-7
  unsigned short* P4 = (unsigned short*)takeB(PAIRB);  // fT0 -> h1T (s8')
  unsigned short* P5 = (unsigned short*)takeB(PAIRB);  // fT1 -> fT5 (s7)
  unsigned short* P6 = (unsigned short*)takeB(PAIRB);  // fT3 -> s9 parts 8-11
  unsigned short* P7 = (unsigned short*)takeB(PAIRB);  // fT2 (s5) -> s9 parts 12-15
  unsigned short* P8 = (unsigned short*)takeB(PAIRB);  // fT4 (s5) -> wpart/dpart
  unsigned short* WThi[6]; unsigned short* WTlo[6];
  for (int i = 0; i < 6; ++i) {
    WThi[i] = (unsigned short*)takeB(WPAIRB);
    WTlo[i] = WThi[i] + (size_t)NDIM * NDIM;
  }
  float* F1 = (float*)takeB(FB);   // h1x f32 (addin for h10)
  float* F3 = (float*)takeB(FB);   // ysum (live to end)

  unsigned short *xhi = P0, *xlo = P0 + E;
  unsigned short *xThi = P1, *xTlo = P1 + E;
  unsigned short *h0hi = P2, *h0lo = P2 + E;
  unsigned short *h0Thi = P3, *h0Tlo = P3 + E;
  float* wpart = (float*)P8; float* dpart = wpart + 64;  // P8 free after s7

  // ---- s1: split x ----
  split_x_k<<<2048, 256, 0, stream>>>(x, xhi, xlo);

  // ---- s2: Weff^T splits (6) + x^T split ----
  {
    TBatch tb{};
    int s = 0;
    for (int i = 0; i < 6; ++i) {
      tb.d[i] = { wbase[i], hebin[i], Wp, WThi[i], WTlo[i], NDIM, NDIM, NDIM / 64, 2 };
      tb.start[i] = s; s += (NDIM / 64) * (NDIM / 64);
    }
    tb.d[6] = { x, nullptr, nullptr, xThi, xTlo, BDIM, NDIM, NDIM / 64, 1 };
    tb.start[6] = s; s += (BDIM / 64) * (NDIM / 64);
    tb.start[7] = s; tb.n = 7;
    transpose_k<<<s, 256, 0, stream>>>(tb);
  }

  auto fwdDesc = [&](const unsigned short* ahi, const unsigned short* alo, int wi) -> GemmDesc {
    GemmDesc d{};
    d.Ahi = ahi; d.Alo = alo; d.Bhi = WThi[wi]; d.Blo = WTlo[wi];
    d.lda = NDIM; d.ldb = NDIM; d.nk = NDIM / 32;
    return d;
  };
  auto hebPart = [&](const unsigned short* ahi, const unsigned short* alo,
                     const unsigned short* bhi, const unsigned short* blo,
                     int koff, int klen, float* partOut) -> GemmDesc {
    GemmDesc d{};
    d.Ahi = ahi + koff; d.Alo = alo + koff;
    d.Bhi = bhi + koff; d.Blo = blo + koff;
    d.lda = BDIM; d.ldb = BDIM; d.nk = klen / 32;
    d.out32a = partOut;
    return d;
  };

  // ---- s3: h0x, h1x, yx (384 blocks) with fused transposed outputs ----
  {
    GemmBatch gb{};
    gb.d[0] = fwdDesc(xhi, xlo, 0);                 // h0x
    gb.d[0].sp_hi = h0hi; gb.d[0].sp_lo = h0lo;     // h0 = relu(h0x) split
    gb.d[0].tr_hi = P4; gb.d[0].tr_lo = P4 + E;     // fT0 = h0x^T split
    gb.d[0].spT_hi = h0Thi; gb.d[0].spT_lo = h0Tlo; // h0T
    gb.d[1] = fwdDesc(xhi, xlo, 1);                 // h1x
    gb.d[1].out32a = F1;
    gb.d[1].tr_hi = P5; gb.d[1].tr_lo = P5 + E;     // fT1 = h1x^T split
    gb.d[2] = fwdDesc(xhi, xlo, 3);                 // yx
    gb.d[2].out32b = F3; gb.d[2].accadd = 0;
    gb.d[2].tr_hi = P6; gb.d[2].tr_lo = P6 + E;     // fT3 = yx^T split
    gb.start[0] = 0; gb.start[1] = 128; gb.start[2] = 256; gb.start[3] = 384;
    gb.n = 3;
    gemm_k<<<384, 256, 0, stream>>>(gb);
  }

  // ---- s5: heb{x2h0,x2h1,x2y} 2-way split-K + h10, y0 (448 blocks) ----
  {
    float* px0a = (float*)WThi[0]; float* px0b = hebout[0];
    float* px1a = (float*)WThi[1]; float* px1b = hebout[1];
    float* pxya = (float*)WThi[3]; float* pxyb = hebout[3];
    GemmBatch gb{};
    gb.d[0] = hebPart(xThi, xTlo, P4, P4 + E, 0,    2048, px0a);  // x2h0
    gb.d[1] = hebPart(xThi, xTlo, P4, P4 + E, 2048, 2048, px0b);
    gb.d[2] = hebPart(xThi, xTlo, P5, P5 + E, 0,    2048, px1a);  // x2h1
    gb.d[3] = hebPart(xThi, xTlo, P5, P5 + E, 2048, 2048, px1b);
    gb.d[4] = hebPart(xThi, xTlo, P6, P6 + E, 0,    2048, pxya);  // x2y
    gb.d[5] = hebPart(xThi, xTlo, P6, P6 + E, 2048, 2048, pxyb);
    gb.d[6] = fwdDesc(h0hi, h0lo, 2);               // h1_0
    gb.d[6].addin = F1;
    gb.d[6].sp_hi = P0; gb.d[6].sp_lo = P0 + E;     // h1 = relu(h1x+h10) split
    gb.d[6].tr_hi = P7; gb.d[6].tr_lo = P7 + E;     // fT2 = h10^T split
    gb.d[7] = fwdDesc(h0hi, h0lo, 4);               // y0
    gb.d[7].out32b = F3; gb.d[7].accadd = 1;
    gb.d[7].tr_hi = P8; gb.d[7].tr_lo = P8 + E;     // fT4 = y0^T split
    for (int i = 0; i < 6; ++i) gb.start[i] = i * 32;
    gb.start[6] = 192; gb.start[7] = 320; gb.start[8] = 448;
    gb.n = 8;
    gemm_k<<<448, 256, 0, stream>>>(gb);
    HebRedB rb{};
    rb.heb_in[0] = hebin[0]; rb.outp[0] = hebout[0]; rb.p[0][0] = px0a; rb.p[0][1] = px0b; rb.np[0] = 2;
    rb.heb_in[1] = hebin[1]; rb.outp[1] = hebout[1]; rb.p[1][0] = px1a; rb.p[1][1] = px1b; rb.np[1] = 2;
    rb.heb_in[2] = hebin[3]; rb.outp[2] = hebout[3]; rb.p[2][0] = pxya; rb.p[2][1] = pxyb; rb.np[2] = 2;
    rb.n = 3;
    hebred_k<<<3072, 256, 0, stream>>>(rb);
  }

  // ---- s8': h1 -> h1T (bf16 pair transpose into P4; fT0 dead) ----
  {
    TBatch tb{};
    tb.d[0] = { P0,     nullptr, nullptr, P4,     nullptr, BDIM, NDIM, NDIM / 64, 0 };
    tb.d[1] = { P0 + E, nullptr, nullptr, P4 + E, nullptr, BDIM, NDIM, NDIM / 64, 0 };
    tb.start[0] = 0; tb.start[1] = 1024; tb.start[2] = 2048; tb.n = 2;
    transpose_k<<<2048, 256, 0, stream>>>(tb);
  }

  // ---- s7: heb{h02h1,h02y} 4-way split-K + y1 (384 blocks) ----
  {
    float* pa[4] = { (float*)WThi[0], (float*)WThi[1], (float*)WThi[2], hebout[2] };
    float* pb[4] = { (float*)WThi[3], (float*)WThi[4], (float*)P2, hebout[4] };
    GemmBatch gb{};
    for (int h = 0; h < 4; ++h) {
      gb.d[h]     = hebPart(h0Thi, h0Tlo, P7, P7 + E, h * 1024, 1024, pa[h]); // h02h1
      gb.d[4 + h] = hebPart(h0Thi, h0Tlo, P8, P8 + E, h * 1024, 1024, pb[h]); // h02y
    }
    gb.d[8] = fwdDesc(P0, P0 + E, 5);               // y1 (A = h1 pair)
    gb.d[8].out32b = F3; gb.d[8].accadd = 1;
    gb.d[8].tr_hi = P5; gb.d[8].tr_lo = P5 + E;     // fT5 = y1^T split (fT1 dead)
    for (int i = 0; i < 8; ++i) gb.start[i] = i * 32;
    gb.start[8] = 256; gb.start[9] = 384;
    gb.n = 9;
    gemm_k<<<384, 256, 0, stream>>>(gb);
    HebRedB rb{};
    rb.heb_in[0] = hebin[2]; rb.outp[0] = hebout[2];
    for (int h = 0; h < 4; ++h) rb.p[0][h] = pa[h];
    rb.np[0] = 4;
    rb.heb_in[1] = hebin[4]; rb.outp[1] = hebout[4];
    for (int h = 0; h < 4; ++h) rb.p[1][h] = pb[h];
    rb.np[1] = 4;
    rb.n = 2;
    hebred_k<<<2048, 256, 0, stream>>>(rb);
  }

  // ---- s9: heb_h12y 16-way split-K (512 blocks) ----
  // partials: P2 (h0 dead), P3 (h0T dead), P6 (fT3 dead), P7 (fT2 dead)
  {
    float* parts[16];
    for (int h = 0; h < 4; ++h) {
      parts[h]      = (float*)P2 + (size_t)h * 1048576;
      parts[4 + h]  = (float*)P3 + (size_t)h * 1048576;
      parts[8 + h]  = (float*)P6 + (size_t)h * 1048576;
      parts[12 + h] = (float*)P7 + (size_t)h * 1048576;
    }
    GemmBatch gb{};
    for (int h = 0; h < 16; ++h)
      gb.d[h] = hebPart(P4, P4 + E, P5, P5 + E, h * 256, 256, parts[h]);
    for (int i = 0; i <= 16; ++i) gb.start[i] = i * 32;
    gb.n = 16;
    gemm_k<<<512, 256, 0, stream>>>(gb);
    HebRedB rb{};
    rb.heb_in[0] = hebin[5]; rb.outp[0] = hebout[5];
    for (int h = 0; h < 16; ++h) rb.p[0][h] = parts[h];
    rb.np[0] = 16;
    rb.n = 1;
    hebred_k<<<1024, 256, 0, stream>>>(rb);
  }

  // ---- s10: y assembly, tanh means (wpart in P8; fT4 dead after s7) ----
  yassm_k<<<2048, 256, 0, stream>>>(F3, out);
  tanhcol_k<<<16, 256, 0, stream>>>(F3, wpart, dpart);
  finalize_k<<<1, 64, 0, stream>>>(wpart, dpart, out, out_size);
}